// Round 6
// baseline (106.989 us; speedup 1.0000x reference)
//
#include <hip/hip_runtime.h>

constexpr int PPT = 4;   // points per thread

// Degree-13 odd tanh on [-3.4,3.4] (clamped), ESTRIN form: same 7 coeffs as
// the Horner version (verified absmax 0.0625), but dependency depth 5 fma
// levels instead of 8 -> per-layer critical path ~36 cyc vs 32 cyc issue,
// so a single wave nearly saturates the VALU issue slots.
__device__ __forceinline__ float tanh_est(float x) {
#if __has_builtin(__builtin_amdgcn_fmed3f)
    float t = __builtin_amdgcn_fmed3f(x, -3.4f, 3.4f);
#else
    float t = fminf(fmaxf(x, -3.4f), 3.4f);
#endif
    float s  = t * t;
    float s2 = s * s;
    float s4 = s2 * s2;
    float e0 = fmaf(s, -3.0595090e-01f, 9.9691910e-01f);
    float e1 = fmaf(s, -1.5874717e-02f, 8.5976700e-02f);
    float e2 = fmaf(s, -1.000059e-04f, 1.7302740e-03f);
    float g0 = fmaf(s2, e1, e0);
    float g1 = fmaf(s2, 2.3524e-06f, e2);
    return t * fmaf(s4, g1, g0);
}

// Flat table in d_ws, ITERATION order, fwd then inv contiguous (128 float4):
//  fwd it (0..15): [it*4+0]=Fm(layer 2it)      [+1]=Fc={C0,C1,+aw,0}
//                  [it*4+2]=Gm(layer 2it+1)    [+3]=Gc={E0,E1,+aw,0}
//  inv it (0..15): [64+it*4+0]=Am(layer 31-2it inv, P-cols sign-folded at 31)
//                  [+1]=Ac={-b0,-b1,-aw,0}
//                  [64+it*4+2]=Bm(layer 30-2it inv)  [+3]=Bc={-b0,-b1,-aw,0}
__global__ void build_tables(const float* __restrict__ act_w,
                             const float* __restrict__ bias_b,
                             const float* __restrict__ lin_w,
                             float4* __restrict__ tab)
{
    int t = threadIdx.x;
    if (t >= 32) return;
    float m00 = 1.f, m01 = 0.f, m10 = 0.f, m11 = 1.f;
    #pragma unroll
    for (int j = 0; j < 8; ++j) {
        float w = lin_w[t * 8 + j];
        if ((j & 1) == 0) { m00 = fmaf(w, m10, m00); m01 = fmaf(w, m11, m01); }
        else              { m10 = fmaf(w, m00, m10); m11 = fmaf(w, m01, m11); }
    }
    float b0 = bias_b[2 * t], b1 = bias_b[2 * t + 1], aw = act_w[t];
    float C0 = fmaf(m00, b0, m01 * b1);
    float C1 = fmaf(m10, b0, m11 * b1);
    if ((t & 1) == 0) {
        tab[(t >> 1) * 4 + 0] = make_float4(m00, m01, m10, m11);
        tab[(t >> 1) * 4 + 1] = make_float4(C0, C1, aw, 0.f);
        int it = (30 - t) >> 1;                    // second-applied in inv iter
        tab[64 + it * 4 + 2] = make_float4(m11, -m01, -m10, m00);
        tab[64 + it * 4 + 3] = make_float4(-b0, -b1, -aw, 0.f);
    } else {
        tab[(t >> 1) * 4 + 2] = make_float4(m00, m01, m10, m11);
        tab[(t >> 1) * 4 + 3] = make_float4(C0, C1, aw, 0.f);
        int it = (31 - t) >> 1;                    // first-applied in inv iter
        // time-reversal (P -> -P) folded into layer 31: negate P-columns
        float s = (t == 31) ? -1.f : 1.f;
        tab[64 + it * 4 + 0] = make_float4(m11, s * (-m01), -m10, s * m00);
        tab[64 + it * 4 + 1] = make_float4(-b0, -b1, -aw, 0.f);
    }
}

__global__ __launch_bounds__(256, 4) void sympnet_main(
    const float* __restrict__ x,
    const float4* __restrict__ tab,
    float* __restrict__ out)
{
    int gid = blockIdx.x * blockDim.x + threadIdx.x;
    const float4* x4 = (const float4*)x;
    float4* out4 = (float4*)out;
    long base = (long)gid * 2;

    float Q[PPT], P[PPT];
    {
        float4 v0 = x4[base], v1 = x4[base + 1];
        Q[0] = v0.x; P[0] = v0.y; Q[1] = v0.z; P[1] = v0.w;
        Q[2] = v1.x; P[2] = v1.y; Q[3] = v1.z; P[3] = v1.w;
    }

    // ---- forward: 16 iterations, table prefetched 1 iteration ahead ----
    float4 Fm = tab[0], Fc = tab[1], Gm = tab[2], Gc = tab[3];
    #pragma unroll 1
    for (int it = 0; it < 16; ++it) {
        const float4* np = tab + (it + 1) * 4;   // it==15 -> inv[0] (contiguous)
        float4 nFm = np[0], nFc = np[1], nGm = np[2], nGc = np[3];
        #pragma unroll
        for (int k = 0; k < PPT; ++k) {
            float Qa = fmaf(Fc.z, tanh_est(P[k]), Q[k]);
            float Qn = fmaf(Fm.x, Qa, fmaf(Fm.y, P[k], Fc.x));
            float Pn = fmaf(Fm.z, Qa, fmaf(Fm.w, P[k], Fc.y));
            float Pa = fmaf(Gc.z, tanh_est(Qn), Pn);
            Q[k] = fmaf(Gm.x, Qn, fmaf(Gm.y, Pa, Gc.x));
            P[k] = fmaf(Gm.z, Qn, fmaf(Gm.w, Pa, Gc.y));
        }
        Fm = nFm; Fc = nFc; Gm = nGm; Gc = nGc;
    }

    // time reversal is folded into inv iter 0's first matrix.

    // ---- inverse: registers already hold inv[0]; prefetch ahead ----
    float4 Am = Fm, Ac = Fc, Bm = Gm, Bc = Gc;
    #pragma unroll 1
    for (int it = 0; it < 16; ++it) {
        int nx = 64 + ((it < 15) ? (it + 1) : it) * 4;   // clamp last (harmless reload)
        const float4* np = tab + nx;
        float4 nAm = np[0], nAc = np[1], nBm = np[2], nBc = np[3];
        #pragma unroll
        for (int k = 0; k < PPT; ++k) {
            float Qn = fmaf(Am.x, Q[k], fmaf(Am.y, P[k], Ac.x));
            float Pn = fmaf(Am.z, Q[k], fmaf(Am.w, P[k], Ac.y));
            Pn = fmaf(Ac.z, tanh_est(Qn), Pn);              // Ac.z = -aw
            float Q2 = fmaf(Bm.x, Qn, fmaf(Bm.y, Pn, Bc.x));
            float P2 = fmaf(Bm.z, Qn, fmaf(Bm.w, Pn, Bc.y));
            Q[k] = fmaf(Bc.z, tanh_est(P2), Q2);            // Bc.z = -aw
            P[k] = P2;
        }
        Am = nAm; Ac = nAc; Bm = nBm; Bc = nBc;
    }

    // final scale [1, -1]
    float4 o0 = make_float4(Q[0], -P[0], Q[1], -P[1]);
    float4 o1 = make_float4(Q[2], -P[2], Q[3], -P[3]);
    out4[base] = o0;
    out4[base + 1] = o1;
}

extern "C" void kernel_launch(void* const* d_in, const int* in_sizes, int n_in,
                              void* d_out, int out_size, void* d_ws, size_t ws_size,
                              hipStream_t stream) {
    const float* x      = (const float*)d_in[0];
    const float* act_w  = (const float*)d_in[1];
    const float* bias_b = (const float*)d_in[2];
    const float* lin_w  = (const float*)d_in[3];
    float* out = (float*)d_out;
    float4* tab = (float4*)d_ws;   // 128 float4 = 2 KB

    build_tables<<<1, 64, 0, stream>>>(act_w, bias_b, lin_w, tab);

    int npts = in_sizes[0] / 2;            // 2097152
    int nthreads = npts / PPT;             // 524288
    int blocks = nthreads / 256;           // 2048 = 8 blocks/CU
    sympnet_main<<<blocks, 256, 0, stream>>>(x, tab, out);
}